// Round 24
// baseline (117.652 us; speedup 1.0000x reference)
//
#include <hip/hip_runtime.h>
#include <hip/hip_bf16.h>
#include <stdint.h>

typedef __attribute__((ext_vector_type(8))) short short8;
typedef __attribute__((ext_vector_type(4))) float f32x4;

#define MFMA(A, B, C) __builtin_amdgcn_mfma_f32_16x16x32_bf16(A, B, C, 0, 0, 0)

__device__ inline uint32_t bfrne(float f) {
  uint32_t u = __float_as_uint(f);
  return (u + 0x7FFFu + ((u >> 16) & 1u)) >> 16;
}

__device__ inline uint32_t pkrne(float a, float b) {
  union { __hip_bfloat162 v; uint32_t u; } c;
  c.v.x = __float2bfloat16(a);
  c.v.y = __float2bfloat16(b);
  return c.u;
}

// raw v_exp_f32 (2^x), no denormal-guard sequence
__device__ inline float fexp2(float x) { return __builtin_amdgcn_exp2f(x); }

__device__ inline void gload16(const short* g, short* l) {
  __builtin_amdgcn_global_load_lds(
      (const __attribute__((address_space(1))) void*)g,
      (__attribute__((address_space(3))) void*)l, 16, 0, 0);
}

// ---------- fused prep: weights + x, all single RNE bf16 ----------
__global__ __launch_bounds__(256) void prep_all_kernel(
    const float* __restrict__ sr_w, const float* __restrict__ kv_w,
    const float* __restrict__ q_w, const float* __restrict__ proj_w,
    const float* __restrict__ x,
    short* __restrict__ WcThi, short* __restrict__ kvThi,
    short* __restrict__ qThi, short* __restrict__ pThi,
    short* __restrict__ xhi) {
  __shared__ float tile[32][33];
  const int blk = blockIdx.x;
  if (blk < 4096) {
    int t = blk * 256 + threadIdx.x;
    int kk = t & 2047, o = t >> 11;
    float v = sr_w[(size_t)o * 2048 + ((kk & 511) << 2) + (kk >> 9)];
    WcThi[t] = (short)bfrne(v);
    return;
  }
  if (blk >= 5120) {
    int t = (blk - 5120) * 256 + threadIdx.x;
    float4 v0 = *(const float4*)&x[(size_t)t * 8];
    float4 v1 = *(const float4*)&x[(size_t)t * 8 + 4];
    uint4 pk;
    pk.x = pkrne(v0.x, v0.y);
    pk.y = pkrne(v0.z, v0.w);
    pk.z = pkrne(v1.x, v1.y);
    pk.w = pkrne(v1.z, v1.w);
    *(uint4*)&xhi[(size_t)t * 8] = pk;
    return;
  }
  const float* in; short* ohi; int N, bx, by;
  if (blk < 4608) {
    in = kv_w; ohi = kvThi; N = 1024;
    int i = blk - 4096; bx = i & 31; by = i >> 5;
  } else if (blk < 4864) {
    in = q_w; ohi = qThi; N = 512;
    int i = blk - 4608; bx = i & 15; by = i >> 4;
  } else {
    in = proj_w; ohi = pThi; N = 512;
    int i = blk - 4864; bx = i & 15; by = i >> 4;
  }
  const int K = 512;
  const int tx = threadIdx.x & 31, ty = threadIdx.x >> 5;
#pragma unroll
  for (int i = 0; i < 4; ++i)
    tile[ty + i * 8][tx] = in[(size_t)(by * 32 + ty + i * 8) * N + bx * 32 + tx];
  __syncthreads();
#pragma unroll
  for (int i = 0; i < 4; ++i) {
    int n = bx * 32 + ty + i * 8;
    float v = tile[tx][ty + i * 8];
    ohi[(size_t)n * K + by * 32 + tx] = (short)bfrne(v);
  }
}

// LayerNorm over 512; input = 4 k-split f32 partials; out single RNE bf16 (packed)
__global__ __launch_bounds__(256) void ln_kernel(
    const float* __restrict__ X, const float* __restrict__ g,
    const float* __restrict__ bta, short* __restrict__ hi) {
  const int row = blockIdx.x, t = threadIdx.x;
  size_t idx = (size_t)row * 512 + t * 2;
  const size_t PS = (size_t)2048 * 512;
  float2 a0 = *(const float2*)&X[idx];
  float2 a1 = *(const float2*)&X[idx + PS];
  float2 a2 = *(const float2*)&X[idx + 2 * PS];
  float2 a3 = *(const float2*)&X[idx + 3 * PS];
  float x0 = a0.x + a1.x + a2.x + a3.x;
  float x1 = a0.y + a1.y + a2.y + a3.y;
  float s = x0 + x1, sq = x0 * x0 + x1 * x1;
#pragma unroll
  for (int off = 1; off < 64; off <<= 1) {
    s += __shfl_xor(s, off);
    sq += __shfl_xor(sq, off);
  }
  __shared__ float rs[4], rq[4];
  int wid = t >> 6;
  if ((t & 63) == 0) { rs[wid] = s; rq[wid] = sq; }
  __syncthreads();
  s = rs[0] + rs[1] + rs[2] + rs[3];
  sq = rq[0] + rq[1] + rq[2] + rq[3];
  float mu = s * (1.f / 512), var = sq * (1.f / 512) - mu * mu;
  float inv = rsqrtf(var + 1e-5f);
  float2 gg = *(const float2*)&g[t * 2], bb = *(const float2*)&bta[t * 2];
  float o0 = (x0 - mu) * inv * gg.x + bb.x;
  float o1 = (x1 - mu) * inv * gg.y + bb.y;
  *(uint32_t*)&hi[idx] = pkrne(o0, o1);
}

// ---------- 64x128 GEMM body (BK=64): kv-scatter (OMODE 2) ----------
template <bool GATHER, int OMODE>
__device__ __forceinline__ void gemm_body(
    short* ldsraw,
    const short* __restrict__ Ahi, const short* __restrict__ BThi,
    const float* __restrict__ bias, float* __restrict__ C,
    short* __restrict__ Chi, short* __restrict__ Vfo, float oscale,
    int M, int N, int lda, int ldb, int klen,
    int bxx, int byy, int bzz) {
  typedef short (*ldsA_t)[64][8];
  typedef short (*ldsB_t)[128][8];
  ldsA_t ldsA = (ldsA_t)ldsraw;                  // [8][64][8]
  ldsB_t ldsB = (ldsB_t)(ldsraw + 8 * 64 * 8);   // [8][128][8]
  const int tid = threadIdx.x, lane = tid & 63, wave = tid >> 6;
  const int g = lane >> 4, qi = lane & 15;
  const int row0 = bxx * 64, col0 = byy * 128;
  const int kz = bzz * klen;
  float* Cz = C + (size_t)bzz * M * N;
  const bool dobias = (bzz == 0);
  f32x4 acc[4][2] = {};

  for (int k0 = kz; k0 < kz + klen; k0 += 64) {
    __syncthreads();
#pragma unroll
    for (int r = 0; r < 2; ++r) {          // A: 64 rows x 8 kg
      int c = tid + r * 256;
      int arow = c & 63, akg = c >> 6;
      size_t ao;
      if (GATHER) {
        int row = row0 + arow;
        int bi = row >> 8, p = row & 255;
        int col = k0 + akg * 8;
        int seg = col >> 9, cc = col & 511;
        int n = (2 * (p >> 4) + (seg >> 1)) * 32 + 2 * (p & 15) + (seg & 1);
        ao = ((size_t)bi * 1024 + n) * 512 + cc;
      } else {
        ao = (size_t)(row0 + arow) * lda + k0 + akg * 8;
      }
      gload16(&Ahi[ao], &ldsA[akg][arow][0]);
    }
#pragma unroll
    for (int r = 0; r < 4; ++r) {          // B: 128 cols x 8 kg
      int c = tid + r * 256;
      int bcol = c & 127, bkg = c >> 7;
      size_t bo = (size_t)(col0 + bcol) * ldb + k0 + bkg * 8;
      gload16(&BThi[bo], &ldsB[bkg][bcol][0]);
    }
    __syncthreads();
#pragma unroll
    for (int kk = 0; kk < 2; ++kk) {
      const int kg = kk * 4 + g;
      short8 ah[4], bh[2];
#pragma unroll
      for (int i = 0; i < 4; ++i)
        ah[i] = *(const short8*)&ldsA[kg][i * 16 + qi][0];
#pragma unroll
      for (int j = 0; j < 2; ++j)
        bh[j] = *(const short8*)&ldsB[kg][wave * 32 + j * 16 + qi][0];
#pragma unroll
      for (int i = 0; i < 4; ++i)
#pragma unroll
        for (int j = 0; j < 2; ++j)
          acc[i][j] = MFMA(ah[i], bh[j], acc[i][j]);
    }
  }
#pragma unroll
  for (int i = 0; i < 4; ++i)
#pragma unroll
    for (int j = 0; j < 2; ++j) {
      int colb = col0 + wave * 32 + j * 16 + qi;
      float bs = dobias ? bias[colb] : 0.f;
#pragma unroll
      for (int r = 0; r < 4; ++r) {
        int row = row0 + i * 16 + g * 4 + r;
        if (OMODE == 0) {
          Cz[(size_t)row * N + colb] = acc[i][j][r] + bs;
        } else {
          // OMODE 2: KV fragment-major scatter (inverse of verified kv_post map)
          uint32_t hv = bfrne(acc[i][j][r] + bs);
          int bb2 = row >> 8, p = row & 255;
          if (colb < 512) {
            int m = p * 8 + (colb >> 6), d = colb & 63;
            size_t t = ((((size_t)(bb2 * 32 + (m >> 6)) * 8 +
                          ((m >> 4) & 3) * 2 + (d >> 5)) * 64) +
                        ((d >> 3) & 3) * 16 + (m & 15)) * 8 + (d & 7);
            Chi[t] = (short)hv;           // Chi = Kf
          } else {
            int c2 = colb - 512;
            int m = p * 8 + (c2 >> 6), d = c2 & 63;
            size_t t = ((((size_t)(bb2 * 32 + (m >> 6)) * 8 +
                          ((m >> 5) & 1) * 4 + (d >> 4)) * 64) +
                        ((m >> 3) & 3) * 16 + (d & 15)) * 8 + (m & 7);
            Vfo[t] = (short)hv;
          }
        }
      }
    }
}

// ---------- 128x128 GEMM body (BK=32, 4 waves 2x2 of 64x64, 4x4 frags) ----------
// 16 MFMAs per 8 ds_read_b128 per wave per k-step. Supports GATHER-A and z-split.
// OMODE 0: f32 out (+bias, z0 only); 1: rne bf16 scaled.
template <bool GATHER, int OMODE>
__device__ __forceinline__ void gemm_sq_body(
    short* ldsraw,
    const short* __restrict__ Ahi, const short* __restrict__ BThi,
    const float* __restrict__ bias, float* __restrict__ C,
    short* __restrict__ Chi, float oscale,
    int M, int N, int lda, int ldb, int klen,
    int bxx, int byy, int bzz) {
  typedef short (*lds_t)[128][8];
  lds_t ldsA = (lds_t)ldsraw;                    // [4][128][8] 8KB
  lds_t ldsB = (lds_t)(ldsraw + 4 * 128 * 8);    // 8KB
  const int tid = threadIdx.x, lane = tid & 63, wave = tid >> 6;
  const int g = lane >> 4, qi = lane & 15;
  const int wr = (wave >> 1) * 64, wc = (wave & 1) * 64;
  const int row0 = bxx * 128, col0 = byy * 128;
  const int kz = bzz * klen;
  float* Cz = C + (size_t)bzz * M * N;
  const bool dobias = (bzz == 0);
  f32x4 acc[4][4] = {};

  for (int k0 = kz; k0 < kz + klen; k0 += 32) {
    __syncthreads();
#pragma unroll
    for (int r = 0; r < 2; ++r) {      // 128 rows x 4 kg each for A and B
      int c = tid + r * 256;
      int arow = c & 127, akg = c >> 7;
      size_t ao;
      if (GATHER) {
        int row = row0 + arow;
        int bi = row >> 8, p = row & 255;
        int col = k0 + akg * 8;
        int seg = col >> 9, cc = col & 511;
        int n = (2 * (p >> 4) + (seg >> 1)) * 32 + 2 * (p & 15) + (seg & 1);
        ao = ((size_t)bi * 1024 + n) * 512 + cc;
      } else {
        ao = (size_t)(row0 + arow) * lda + k0 + akg * 8;
      }
      gload16(&Ahi[ao], &ldsA[akg][arow][0]);
      gload16(&BThi[(size_t)(col0 + arow) * ldb + k0 + akg * 8], &ldsB[akg][arow][0]);
    }
    __syncthreads();
    short8 ah[4], bh[4];
#pragma unroll
    for (int i = 0; i < 4; ++i) {
      ah[i] = *(const short8*)&ldsA[g][wr + i * 16 + qi][0];
      bh[i] = *(const short8*)&ldsB[g][wc + i * 16 + qi][0];
    }
#pragma unroll
    for (int i = 0; i < 4; ++i)
#pragma unroll
      for (int j = 0; j < 4; ++j)
        acc[i][j] = MFMA(ah[i], bh[j], acc[i][j]);
  }
#pragma unroll
  for (int i = 0; i < 4; ++i)
#pragma unroll
    for (int j = 0; j < 4; ++j) {
      int colb = col0 + wc + j * 16 + qi;
      float bs = dobias ? bias[colb] : 0.f;
#pragma unroll
      for (int r = 0; r < 4; ++r) {
        int row = row0 + wr + i * 16 + g * 4 + r;
        if (OMODE == 0) {
          Cz[(size_t)row * N + colb] = acc[i][j][r] + bs;
        } else {
          Chi[(size_t)row * N + colb] = (short)bfrne((acc[i][j][r] + bs) * oscale);
        }
      }
    }
}

template <bool GATHER, int OMODE>
__global__ __launch_bounds__(256) void gemm_sq(
    const short* __restrict__ Ahi, const short* __restrict__ BThi,
    const float* __restrict__ bias, float* __restrict__ C,
    short* __restrict__ Chi, float oscale,
    int M, int N, int lda, int ldb, int klen) {
  __shared__ short lds[8192];   // 16KB
  gemm_sq_body<GATHER, OMODE>(lds, Ahi, BThi, bias, C, Chi, oscale,
                              M, N, lda, ldb, klen,
                              blockIdx.x, blockIdx.y, blockIdx.z);
}

// fused conv-GEMM (256 blocks, 128x128 GATHER z4) + Q-GEMM (256 blocks, 128x128)
__global__ __launch_bounds__(256) void conv_q_kernel(
    const short* __restrict__ xhi, const short* __restrict__ WcThi,
    const float* __restrict__ sr_b, float* __restrict__ Cbuf,
    const short* __restrict__ qThi, const float* __restrict__ q_b,
    short* __restrict__ Qhi, float qscale) {
  __shared__ short lds[8192];   // 16KB
  const int blk = blockIdx.x;
  if (blk < 256) {
    int bx = blk & 15, by = (blk >> 4) & 3, bz = blk >> 6;   // bz in {0..3}
    gemm_sq_body<true, 0>(lds, xhi, WcThi, sr_b, Cbuf, nullptr, 1.f,
                          2048, 512, 512, 2048, 512, bx, by, bz);
  } else {
    int i = blk - 256;
    int bx = i & 63, by = i >> 6;        // 64 x 4
    gemm_sq_body<false, 1>(lds, xhi, qThi, q_b, nullptr, Qhi, qscale,
                           8192, 512, 512, 512, 512, bx, by, 0);
  }
}

// kv-GEMM wrapper (64x128 body, OMODE 2 scatter)
__global__ __launch_bounds__(256) void kv_gemm_kernel(
    const short* __restrict__ LNhi, const short* __restrict__ kvThi,
    const float* __restrict__ kv_b, short* __restrict__ Kf, short* __restrict__ Vf) {
  __shared__ short lds[12288];
  gemm_body<false, 2>(lds, LNhi, kvThi, kv_b, nullptr, Kf, Vf, 1.f,
                      2048, 1024, 512, 512, 512,
                      blockIdx.x, blockIdx.y, 0);
}

// ---------- barrier-free MFMA flash attention, 2-deep pipeline (R16/R20-proven) ----------
__device__ __forceinline__ void ld8(short8 (&dst)[8], const short* base) {
#pragma unroll
  for (int i = 0; i < 8; ++i)
    dst[i] = *(const short8*)&base[(size_t)i * 512];
}

__device__ __forceinline__ void qk_tile(f32x4 (&s)[2][4], const short8 (&kr)[8],
                                        const short8 (&qh)[2][2]) {
  const f32x4 z = {0.f, 0.f, 0.f, 0.f};
  __builtin_amdgcn_s_setprio(1);
#pragma unroll
  for (int mf = 0; mf < 4; ++mf)
#pragma unroll
    for (int qc = 0; qc < 2; ++qc) {
      s[qc][mf] = MFMA(kr[mf * 2 + 0], qh[qc][0], z);
      s[qc][mf] = MFMA(kr[mf * 2 + 1], qh[qc][1], s[qc][mf]);
    }
  __builtin_amdgcn_s_setprio(0);
}

__device__ __forceinline__ void pack_tile(const f32x4 (&s)[2][4], short* Psw,
                                          int g, int qi, int swz) {
#pragma unroll
  for (int qc = 0; qc < 2; ++qc)
#pragma unroll
    for (int mf = 0; mf < 4; ++mf) {
      uint32_t u0 = __float_as_uint(fexp2(s[qc][mf][0]));
      uint32_t u1 = __float_as_uint(fexp2(s[qc][mf][1]));
      uint32_t u2 = __float_as_uint(fexp2(s[qc][mf][2]));
      uint32_t u3 = __float_as_uint(fexp2(s[qc][mf][3]));
      uint2 hp;
      hp.x = (u0 >> 16) | (u1 & 0xffff0000u);
      hp.y = (u2 >> 16) | (u3 & 0xffff0000u);
      int uw = ((mf * 4 + g) ^ swz) << 2;
      *(uint2*)&Psw[qc * 1024 + qi * 64 + uw] = hp;
    }
}

__device__ __forceinline__ void pv_tile(const short8 (&vr)[8], short* Psw,
                                        f32x4 (&lacc)[2], f32x4 (&oacc)[2][4],
                                        int g, int qi, int swz) {
  const short8 ones = {(short)0x3F80, (short)0x3F80, (short)0x3F80, (short)0x3F80,
                       (short)0x3F80, (short)0x3F80, (short)0x3F80, (short)0x3F80};
#pragma unroll
  for (int qc = 0; qc < 2; ++qc)
#pragma unroll
    for (int ks2 = 0; ks2 < 2; ++ks2) {
      int ur = ((ks2 * 8 + g * 2) ^ swz) << 2;
      short8 pa = *(const short8*)&Psw[qc * 1024 + qi * 64 + ur];
      __builtin_amdgcn_s_setprio(1);
      lacc[qc] = MFMA(ones, pa, lacc[qc]);
#pragma unroll
      for (int df = 0; df < 4; ++df)
        oacc[qc][df] = MFMA(vr[ks2 * 4 + df], pa, oacc[qc][df]);
      __builtin_amdgcn_s_setprio(0);
    }
}

__global__ __launch_bounds__(256, 2) void attn_kernel(
    const short* __restrict__ Qhi, const short* __restrict__ Kf,
    const short* __restrict__ Vf, short* __restrict__ Ohi) {
  __shared__ short Ps[4][2][1024];   // per-wave P bounce, 16KB total
  const int tid = threadIdx.x, lane = tid & 63, wave = tid >> 6;
  const int g = lane >> 4, qi = lane & 15;
  const int h = blockIdx.y, b = blockIdx.z;
  const int n0 = blockIdx.x * 128 + wave * 32;
  const int swz = (qi & 7) << 1;
  short* Psw = &Ps[wave][0][0];

  short8 qh[2][2];
#pragma unroll
  for (int qc = 0; qc < 2; ++qc) {
    const size_t qrow = ((size_t)b * 1024 + n0 + qc * 16 + qi) * 512 + h * 64;
#pragma unroll
    for (int ks = 0; ks < 2; ++ks)
      qh[qc][ks] = *(const short8*)&Qhi[qrow + (ks * 4 + g) * 8];
  }
  f32x4 lacc[2] = {};
  f32x4 oacc[2][4] = {};
  const short* Kb = Kf + (size_t)b * 131072 + lane * 8;
  const short* Vb = Vf + (size_t)b * 131072 + lane * 8;

  short8 kA[8], kB[8], vr[8];
  f32x4 sA[2][4], sB[2][4];
  ld8(kA, Kb);
  ld8(kB, Kb + 4096);
  qk_tile(sA, kA, qh);
  for (int t = 0; t < 32; t += 2) {
    const short* tK = Kb + (size_t)t * 4096;
    const short* tV = Vb + (size_t)t * 4096;
    ld8(vr, tV);                        // V(t)
    if (t < 30) ld8(kA, tK + 8192);     // K(t+2)
    pack_tile(sA, Psw, g, qi, swz);
    qk_tile(sB, kB, qh);                // s(t+1)
    pv_tile(vr, Psw, lacc, oacc, g, qi, swz);
    ld8(vr, tV + 4096);                 // V(t+1)
    if (t < 30) ld8(kB, tK + 12288);    // K(t+3)
    pack_tile(sB, Psw, g, qi, swz);
    if (t < 30) qk_tile(sA, kA, qh);    // s(t+2)
    pv_tile(vr, Psw, lacc, oacc, g, qi, swz);
  }
#pragma unroll
  for (int qc = 0; qc < 2; ++qc) {
    float linv = 1.f / lacc[qc][0];
    size_t obase = ((size_t)b * 1024 + n0 + qc * 16 + qi) * 512 + h * 64;
#pragma unroll
    for (int df = 0; df < 4; ++df) {
      float o0 = oacc[qc][df][0] * linv, o1 = oacc[qc][df][1] * linv;
      float o2 = oacc[qc][df][2] * linv, o3 = oacc[qc][df][3] * linv;
      uint2 hp;
      hp.x = pkrne(o0, o1);
      hp.y = pkrne(o2, o3);
      *(uint2*)&Ohi[obase + df * 16 + g * 4] = hp;
    }
  }
}

// ---------- launcher ----------
extern "C" void kernel_launch(void* const* d_in, const int* in_sizes, int n_in,
                              void* d_out, int out_size, void* d_ws, size_t ws_size,
                              hipStream_t stream) {
  const float* x      = (const float*)d_in[0];
  const float* q_w    = (const float*)d_in[3];
  const float* q_b    = (const float*)d_in[4];
  const float* kv_w   = (const float*)d_in[5];
  const float* kv_b   = (const float*)d_in[6];
  const float* sr_w   = (const float*)d_in[7];
  const float* sr_b   = (const float*)d_in[8];
  const float* ln_g   = (const float*)d_in[9];
  const float* ln_b   = (const float*)d_in[10];
  const float* proj_w = (const float*)d_in[11];
  const float* proj_b = (const float*)d_in[12];

  char* W = (char*)d_ws;
  const size_t MB = 1024 * 1024;
  short* xhi   = (short*)(W);                  // 0-8
  short* WcThi = (short*)(W + 16 * MB);        // 16-18
  float* Cbuf  = (float*)(W + 20 * MB);        // 20-36 (4 partials x 4MB)
  short* LNhi  = (short*)(W + 36 * MB);        // 36-38
  short* kvThi = (short*)(W + 40 * MB);        // 40-41
  short* qThi  = (short*)(W + 42 * MB);        // 42-42.5
  short* pThi  = (short*)(W + 43 * MB);        // 43-43.5
  short* Qhi   = (short*)(W + 44 * MB);        // 44-52 (written by conv_q)
  short* Kf    = (short*)(W + 16 * MB);        // 16-18 (WcThi dead after conv_q)
  short* Vf    = (short*)(W + 18 * MB);        // 18-20
  short* Ohi   = (short*)(W);                  // 0-8 (xhi dead after conv_q)

  prep_all_kernel<<<7168, 256, 0, stream>>>(
      sr_w, kv_w, q_w, proj_w, x, WcThi, kvThi, qThi, pThi, xhi);
  conv_q_kernel<<<512, 256, 0, stream>>>(
      xhi, WcThi, sr_b, Cbuf, qThi, q_b, Qhi, 0.125f * 1.44269504f);
  ln_kernel<<<2048, 256, 0, stream>>>(Cbuf, ln_g, ln_b, LNhi);
  kv_gemm_kernel<<<dim3(32, 8), 256, 0, stream>>>(LNhi, kvThi, kv_b, Kf, Vf);
  attn_kernel<<<dim3(8, 8, 8), 256, 0, stream>>>(Qhi, Kf, Vf, Ohi);
  gemm_sq<false, 0><<<dim3(64, 4, 1), 256, 0, stream>>>(
      Ohi, pThi, proj_b, (float*)d_out, nullptr, 1.f, 8192, 512, 512, 512, 512);
}

// Round 25
// 115.772 us; speedup vs baseline: 1.0162x; 1.0162x over previous
//
#include <hip/hip_runtime.h>
#include <hip/hip_bf16.h>
#include <stdint.h>

typedef __attribute__((ext_vector_type(8))) short short8;
typedef __attribute__((ext_vector_type(4))) float f32x4;

#define MFMA(A, B, C) __builtin_amdgcn_mfma_f32_16x16x32_bf16(A, B, C, 0, 0, 0)

__device__ inline uint32_t bfrne(float f) {
  uint32_t u = __float_as_uint(f);
  return (u + 0x7FFFu + ((u >> 16) & 1u)) >> 16;
}

__device__ inline uint32_t pkrne(float a, float b) {
  union { __hip_bfloat162 v; uint32_t u; } c;
  c.v.x = __float2bfloat16(a);
  c.v.y = __float2bfloat16(b);
  return c.u;
}

// raw v_exp_f32 (2^x), no denormal-guard sequence
__device__ inline float fexp2(float x) { return __builtin_amdgcn_exp2f(x); }

__device__ inline void gload16(const short* g, short* l) {
  __builtin_amdgcn_global_load_lds(
      (const __attribute__((address_space(1))) void*)g,
      (__attribute__((address_space(3))) void*)l, 16, 0, 0);
}

// ---------- fused prep: weights + x, all single RNE bf16 ----------
__global__ __launch_bounds__(256) void prep_all_kernel(
    const float* __restrict__ sr_w, const float* __restrict__ kv_w,
    const float* __restrict__ q_w, const float* __restrict__ proj_w,
    const float* __restrict__ x,
    short* __restrict__ WcThi, short* __restrict__ kvThi,
    short* __restrict__ qThi, short* __restrict__ pThi,
    short* __restrict__ xhi) {
  __shared__ float tile[32][33];
  const int blk = blockIdx.x;
  if (blk < 4096) {
    int t = blk * 256 + threadIdx.x;
    int kk = t & 2047, o = t >> 11;
    float v = sr_w[(size_t)o * 2048 + ((kk & 511) << 2) + (kk >> 9)];
    WcThi[t] = (short)bfrne(v);
    return;
  }
  if (blk >= 5120) {
    int t = (blk - 5120) * 256 + threadIdx.x;
    float4 v0 = *(const float4*)&x[(size_t)t * 8];
    float4 v1 = *(const float4*)&x[(size_t)t * 8 + 4];
    uint4 pk;
    pk.x = pkrne(v0.x, v0.y);
    pk.y = pkrne(v0.z, v0.w);
    pk.z = pkrne(v1.x, v1.y);
    pk.w = pkrne(v1.z, v1.w);
    *(uint4*)&xhi[(size_t)t * 8] = pk;
    return;
  }
  const float* in; short* ohi; int N, bx, by;
  if (blk < 4608) {
    in = kv_w; ohi = kvThi; N = 1024;
    int i = blk - 4096; bx = i & 31; by = i >> 5;
  } else if (blk < 4864) {
    in = q_w; ohi = qThi; N = 512;
    int i = blk - 4608; bx = i & 15; by = i >> 4;
  } else {
    in = proj_w; ohi = pThi; N = 512;
    int i = blk - 4864; bx = i & 15; by = i >> 4;
  }
  const int K = 512;
  const int tx = threadIdx.x & 31, ty = threadIdx.x >> 5;
#pragma unroll
  for (int i = 0; i < 4; ++i)
    tile[ty + i * 8][tx] = in[(size_t)(by * 32 + ty + i * 8) * N + bx * 32 + tx];
  __syncthreads();
#pragma unroll
  for (int i = 0; i < 4; ++i) {
    int n = bx * 32 + ty + i * 8;
    float v = tile[tx][ty + i * 8];
    ohi[(size_t)n * K + by * 32 + tx] = (short)bfrne(v);
  }
}

// LayerNorm over 512; input = 2 k-split f32 partials; out single RNE bf16 (packed)
__global__ __launch_bounds__(256) void ln_kernel(
    const float* __restrict__ X, const float* __restrict__ g,
    const float* __restrict__ bta, short* __restrict__ hi) {
  const int row = blockIdx.x, t = threadIdx.x;
  size_t idx = (size_t)row * 512 + t * 2;
  const size_t PS = (size_t)2048 * 512;
  float2 a0 = *(const float2*)&X[idx];
  float2 a1 = *(const float2*)&X[idx + PS];
  float x0 = a0.x + a1.x;
  float x1 = a0.y + a1.y;
  float s = x0 + x1, sq = x0 * x0 + x1 * x1;
#pragma unroll
  for (int off = 1; off < 64; off <<= 1) {
    s += __shfl_xor(s, off);
    sq += __shfl_xor(sq, off);
  }
  __shared__ float rs[4], rq[4];
  int wid = t >> 6;
  if ((t & 63) == 0) { rs[wid] = s; rq[wid] = sq; }
  __syncthreads();
  s = rs[0] + rs[1] + rs[2] + rs[3];
  sq = rq[0] + rq[1] + rq[2] + rq[3];
  float mu = s * (1.f / 512), var = sq * (1.f / 512) - mu * mu;
  float inv = rsqrtf(var + 1e-5f);
  float2 gg = *(const float2*)&g[t * 2], bb = *(const float2*)&bta[t * 2];
  float o0 = (x0 - mu) * inv * gg.x + bb.x;
  float o1 = (x1 - mu) * inv * gg.y + bb.y;
  *(uint32_t*)&hi[idx] = pkrne(o0, o1);
}

// ---------- 64x128 GEMM body (BK=64): conv (GATHER) + kv-scatter ----------
// OMODE 0: f32 out (+bias). OMODE 2: KV fragment-major scatter, rne bf16.
template <bool GATHER, int OMODE>
__device__ __forceinline__ void gemm_body(
    short* ldsraw,
    const short* __restrict__ Ahi, const short* __restrict__ BThi,
    const float* __restrict__ bias, float* __restrict__ C,
    short* __restrict__ Chi, short* __restrict__ Vfo, float oscale,
    int M, int N, int lda, int ldb, int klen,
    int bxx, int byy, int bzz) {
  typedef short (*ldsA_t)[64][8];
  typedef short (*ldsB_t)[128][8];
  ldsA_t ldsA = (ldsA_t)ldsraw;                  // [8][64][8]
  ldsB_t ldsB = (ldsB_t)(ldsraw + 8 * 64 * 8);   // [8][128][8]
  const int tid = threadIdx.x, lane = tid & 63, wave = tid >> 6;
  const int g = lane >> 4, qi = lane & 15;
  const int row0 = bxx * 64, col0 = byy * 128;
  const int kz = bzz * klen;
  float* Cz = C + (size_t)bzz * M * N;
  const bool dobias = (bzz == 0);
  f32x4 acc[4][2] = {};

  for (int k0 = kz; k0 < kz + klen; k0 += 64) {
    __syncthreads();
#pragma unroll
    for (int r = 0; r < 2; ++r) {          // A: 64 rows x 8 kg
      int c = tid + r * 256;
      int arow = c & 63, akg = c >> 6;
      size_t ao;
      if (GATHER) {
        int row = row0 + arow;
        int bi = row >> 8, p = row & 255;
        int col = k0 + akg * 8;
        int seg = col >> 9, cc = col & 511;
        int n = (2 * (p >> 4) + (seg >> 1)) * 32 + 2 * (p & 15) + (seg & 1);
        ao = ((size_t)bi * 1024 + n) * 512 + cc;
      } else {
        ao = (size_t)(row0 + arow) * lda + k0 + akg * 8;
      }
      gload16(&Ahi[ao], &ldsA[akg][arow][0]);
    }
#pragma unroll
    for (int r = 0; r < 4; ++r) {          // B: 128 cols x 8 kg
      int c = tid + r * 256;
      int bcol = c & 127, bkg = c >> 7;
      size_t bo = (size_t)(col0 + bcol) * ldb + k0 + bkg * 8;
      gload16(&BThi[bo], &ldsB[bkg][bcol][0]);
    }
    __syncthreads();
#pragma unroll
    for (int kk = 0; kk < 2; ++kk) {
      const int kg = kk * 4 + g;
      short8 ah[4], bh[2];
#pragma unroll
      for (int i = 0; i < 4; ++i)
        ah[i] = *(const short8*)&ldsA[kg][i * 16 + qi][0];
#pragma unroll
      for (int j = 0; j < 2; ++j)
        bh[j] = *(const short8*)&ldsB[kg][wave * 32 + j * 16 + qi][0];
#pragma unroll
      for (int i = 0; i < 4; ++i)
#pragma unroll
        for (int j = 0; j < 2; ++j)
          acc[i][j] = MFMA(ah[i], bh[j], acc[i][j]);
    }
  }
#pragma unroll
  for (int i = 0; i < 4; ++i)
#pragma unroll
    for (int j = 0; j < 2; ++j) {
      int colb = col0 + wave * 32 + j * 16 + qi;
      float bs = dobias ? bias[colb] : 0.f;
#pragma unroll
      for (int r = 0; r < 4; ++r) {
        int row = row0 + i * 16 + g * 4 + r;
        if (OMODE == 0) {
          Cz[(size_t)row * N + colb] = acc[i][j][r] + bs;
        } else {
          // OMODE 2: KV fragment-major scatter (inverse of verified kv_post map)
          uint32_t hv = bfrne(acc[i][j][r] + bs);
          int bb2 = row >> 8, p = row & 255;
          if (colb < 512) {
            int m = p * 8 + (colb >> 6), d = colb & 63;
            size_t t = ((((size_t)(bb2 * 32 + (m >> 6)) * 8 +
                          ((m >> 4) & 3) * 2 + (d >> 5)) * 64) +
                        ((d >> 3) & 3) * 16 + (m & 15)) * 8 + (d & 7);
            Chi[t] = (short)hv;           // Chi = Kf
          } else {
            int c2 = colb - 512;
            int m = p * 8 + (c2 >> 6), d = c2 & 63;
            size_t t = ((((size_t)(bb2 * 32 + (m >> 6)) * 8 +
                          ((m >> 5) & 1) * 4 + (d >> 4)) * 64) +
                        ((m >> 3) & 3) * 16 + (d & 15)) * 8 + (m & 7);
            Vfo[t] = (short)hv;
          }
        }
      }
    }
}

// ---------- 128x128 GEMM body (BK=32, 4 waves 2x2 of 64x64, 4x4 frags) ----------
// 16 MFMAs per 8 ds_read_b128 per wave per k-step. OMODE 0: f32+bias; 1: bf16 scaled.
template <int OMODE>
__device__ __forceinline__ void gemm_sq_body(
    short* ldsraw,
    const short* __restrict__ Ahi, const short* __restrict__ BThi,
    const float* __restrict__ bias, float* __restrict__ C,
    short* __restrict__ Chi, float oscale,
    int M, int N, int lda, int ldb, int bxx, int byy) {
  typedef short (*lds_t)[128][8];
  lds_t ldsA = (lds_t)ldsraw;                    // [4][128][8] 8KB
  lds_t ldsB = (lds_t)(ldsraw + 4 * 128 * 8);    // 8KB
  const int tid = threadIdx.x, lane = tid & 63, wave = tid >> 6;
  const int g = lane >> 4, qi = lane & 15;
  const int wr = (wave >> 1) * 64, wc = (wave & 1) * 64;
  const int row0 = bxx * 128, col0 = byy * 128;
  f32x4 acc[4][4] = {};

  for (int k0 = 0; k0 < 512; k0 += 32) {
    __syncthreads();
#pragma unroll
    for (int r = 0; r < 2; ++r) {      // 128 rows x 4 kg each for A and B
      int c = tid + r * 256;
      int arow = c & 127, akg = c >> 7;
      gload16(&Ahi[(size_t)(row0 + arow) * lda + k0 + akg * 8], &ldsA[akg][arow][0]);
      gload16(&BThi[(size_t)(col0 + arow) * ldb + k0 + akg * 8], &ldsB[akg][arow][0]);
    }
    __syncthreads();
    short8 ah[4], bh[4];
#pragma unroll
    for (int i = 0; i < 4; ++i) {
      ah[i] = *(const short8*)&ldsA[g][wr + i * 16 + qi][0];
      bh[i] = *(const short8*)&ldsB[g][wc + i * 16 + qi][0];
    }
#pragma unroll
    for (int i = 0; i < 4; ++i)
#pragma unroll
      for (int j = 0; j < 4; ++j)
        acc[i][j] = MFMA(ah[i], bh[j], acc[i][j]);
  }
#pragma unroll
  for (int i = 0; i < 4; ++i)
#pragma unroll
    for (int j = 0; j < 4; ++j) {
      int colb = col0 + wc + j * 16 + qi;
      float bs = bias[colb];
#pragma unroll
      for (int r = 0; r < 4; ++r) {
        int row = row0 + wr + i * 16 + g * 4 + r;
        if (OMODE == 0) {
          C[(size_t)row * N + colb] = acc[i][j][r] + bs;
        } else {
          Chi[(size_t)row * N + colb] = (short)bfrne((acc[i][j][r] + bs) * oscale);
        }
      }
    }
}

template <int OMODE>
__global__ __launch_bounds__(256) void gemm_sq(
    const short* __restrict__ Ahi, const short* __restrict__ BThi,
    const float* __restrict__ bias, float* __restrict__ C,
    short* __restrict__ Chi, float oscale,
    int M, int N, int lda, int ldb) {
  __shared__ short lds[8192];   // 16KB
  gemm_sq_body<OMODE>(lds, Ahi, BThi, bias, C, Chi, oscale,
                      M, N, lda, ldb, blockIdx.x, blockIdx.y);
}

// fused conv-GEMM (256 blocks, 64x128/BK=64/z2) + Q-GEMM (256 blocks, 128x128)
__global__ __launch_bounds__(256) void conv_q_kernel(
    const short* __restrict__ xhi, const short* __restrict__ WcThi,
    const float* __restrict__ sr_b, float* __restrict__ Cbuf,
    const short* __restrict__ qThi, const float* __restrict__ q_b,
    short* __restrict__ Qhi, float qscale) {
  __shared__ short lds[12288];   // 24KB (max of both bodies)
  const int blk = blockIdx.x;
  if (blk < 256) {
    int bx = blk & 31, by = (blk >> 5) & 3, bz = blk >> 7;   // bz in {0,1}
    gemm_body<true, 0>(lds, xhi, WcThi, sr_b, Cbuf, nullptr, nullptr, 1.f,
                       2048, 512, 512, 2048, 1024, bx, by, bz);
  } else {
    int i = blk - 256;
    int bx = i & 63, by = i >> 6;        // 64 x 4
    gemm_sq_body<1>(lds, xhi, qThi, q_b, nullptr, Qhi, qscale,
                    8192, 512, 512, 512, bx, by);
  }
}

// kv-GEMM wrapper (64x128 body, OMODE 2 scatter)
__global__ __launch_bounds__(256) void kv_gemm_kernel(
    const short* __restrict__ LNhi, const short* __restrict__ kvThi,
    const float* __restrict__ kv_b, short* __restrict__ Kf, short* __restrict__ Vf) {
  __shared__ short lds[12288];
  gemm_body<false, 2>(lds, LNhi, kvThi, kv_b, nullptr, Kf, Vf, 1.f,
                      2048, 1024, 512, 512, 512,
                      blockIdx.x, blockIdx.y, 0);
}

// ---------- barrier-free MFMA flash attention, 2-deep pipeline (R16/R20-proven) ----------
__device__ __forceinline__ void ld8(short8 (&dst)[8], const short* base) {
#pragma unroll
  for (int i = 0; i < 8; ++i)
    dst[i] = *(const short8*)&base[(size_t)i * 512];
}

__device__ __forceinline__ void qk_tile(f32x4 (&s)[2][4], const short8 (&kr)[8],
                                        const short8 (&qh)[2][2]) {
  const f32x4 z = {0.f, 0.f, 0.f, 0.f};
  __builtin_amdgcn_s_setprio(1);
#pragma unroll
  for (int mf = 0; mf < 4; ++mf)
#pragma unroll
    for (int qc = 0; qc < 2; ++qc) {
      s[qc][mf] = MFMA(kr[mf * 2 + 0], qh[qc][0], z);
      s[qc][mf] = MFMA(kr[mf * 2 + 1], qh[qc][1], s[qc][mf]);
    }
  __builtin_amdgcn_s_setprio(0);
}

__device__ __forceinline__ void pack_tile(const f32x4 (&s)[2][4], short* Psw,
                                          int g, int qi, int swz) {
#pragma unroll
  for (int qc = 0; qc < 2; ++qc)
#pragma unroll
    for (int mf = 0; mf < 4; ++mf) {
      uint32_t u0 = __float_as_uint(fexp2(s[qc][mf][0]));
      uint32_t u1 = __float_as_uint(fexp2(s[qc][mf][1]));
      uint32_t u2 = __float_as_uint(fexp2(s[qc][mf][2]));
      uint32_t u3 = __float_as_uint(fexp2(s[qc][mf][3]));
      uint2 hp;
      hp.x = (u0 >> 16) | (u1 & 0xffff0000u);
      hp.y = (u2 >> 16) | (u3 & 0xffff0000u);
      int uw = ((mf * 4 + g) ^ swz) << 2;
      *(uint2*)&Psw[qc * 1024 + qi * 64 + uw] = hp;
    }
}

__device__ __forceinline__ void pv_tile(const short8 (&vr)[8], short* Psw,
                                        f32x4 (&lacc)[2], f32x4 (&oacc)[2][4],
                                        int g, int qi, int swz) {
  const short8 ones = {(short)0x3F80, (short)0x3F80, (short)0x3F80, (short)0x3F80,
                       (short)0x3F80, (short)0x3F80, (short)0x3F80, (short)0x3F80};
#pragma unroll
  for (int qc = 0; qc < 2; ++qc)
#pragma unroll
    for (int ks2 = 0; ks2 < 2; ++ks2) {
      int ur = ((ks2 * 8 + g * 2) ^ swz) << 2;
      short8 pa = *(const short8*)&Psw[qc * 1024 + qi * 64 + ur];
      __builtin_amdgcn_s_setprio(1);
      lacc[qc] = MFMA(ones, pa, lacc[qc]);
#pragma unroll
      for (int df = 0; df < 4; ++df)
        oacc[qc][df] = MFMA(vr[ks2 * 4 + df], pa, oacc[qc][df]);
      __builtin_amdgcn_s_setprio(0);
    }
}

__global__ __launch_bounds__(256, 2) void attn_kernel(
    const short* __restrict__ Qhi, const short* __restrict__ Kf,
    const short* __restrict__ Vf, short* __restrict__ Ohi) {
  __shared__ short Ps[4][2][1024];   // per-wave P bounce, 16KB total
  const int tid = threadIdx.x, lane = tid & 63, wave = tid >> 6;
  const int g = lane >> 4, qi = lane & 15;
  const int h = blockIdx.y, b = blockIdx.z;
  const int n0 = blockIdx.x * 128 + wave * 32;
  const int swz = (qi & 7) << 1;
  short* Psw = &Ps[wave][0][0];

  short8 qh[2][2];
#pragma unroll
  for (int qc = 0; qc < 2; ++qc) {
    const size_t qrow = ((size_t)b * 1024 + n0 + qc * 16 + qi) * 512 + h * 64;
#pragma unroll
    for (int ks = 0; ks < 2; ++ks)
      qh[qc][ks] = *(const short8*)&Qhi[qrow + (ks * 4 + g) * 8];
  }
  f32x4 lacc[2] = {};
  f32x4 oacc[2][4] = {};
  const short* Kb = Kf + (size_t)b * 131072 + lane * 8;
  const short* Vb = Vf + (size_t)b * 131072 + lane * 8;

  short8 kA[8], kB[8], vr[8];
  f32x4 sA[2][4], sB[2][4];
  ld8(kA, Kb);
  ld8(kB, Kb + 4096);
  qk_tile(sA, kA, qh);
  for (int t = 0; t < 32; t += 2) {
    const short* tK = Kb + (size_t)t * 4096;
    const short* tV = Vb + (size_t)t * 4096;
    ld8(vr, tV);                        // V(t)
    if (t < 30) ld8(kA, tK + 8192);     // K(t+2)
    pack_tile(sA, Psw, g, qi, swz);
    qk_tile(sB, kB, qh);                // s(t+1)
    pv_tile(vr, Psw, lacc, oacc, g, qi, swz);
    ld8(vr, tV + 4096);                 // V(t+1)
    if (t < 30) ld8(kB, tK + 12288);    // K(t+3)
    pack_tile(sB, Psw, g, qi, swz);
    if (t < 30) qk_tile(sA, kA, qh);    // s(t+2)
    pv_tile(vr, Psw, lacc, oacc, g, qi, swz);
  }
#pragma unroll
  for (int qc = 0; qc < 2; ++qc) {
    float linv = 1.f / lacc[qc][0];
    size_t obase = ((size_t)b * 1024 + n0 + qc * 16 + qi) * 512 + h * 64;
#pragma unroll
    for (int df = 0; df < 4; ++df) {
      float o0 = oacc[qc][df][0] * linv, o1 = oacc[qc][df][1] * linv;
      float o2 = oacc[qc][df][2] * linv, o3 = oacc[qc][df][3] * linv;
      uint2 hp;
      hp.x = pkrne(o0, o1);
      hp.y = pkrne(o2, o3);
      *(uint2*)&Ohi[obase + df * 16 + g * 4] = hp;
    }
  }
}

// ---------- launcher ----------
extern "C" void kernel_launch(void* const* d_in, const int* in_sizes, int n_in,
                              void* d_out, int out_size, void* d_ws, size_t ws_size,
                              hipStream_t stream) {
  const float* x      = (const float*)d_in[0];
  const float* q_w    = (const float*)d_in[3];
  const float* q_b    = (const float*)d_in[4];
  const float* kv_w   = (const float*)d_in[5];
  const float* kv_b   = (const float*)d_in[6];
  const float* sr_w   = (const float*)d_in[7];
  const float* sr_b   = (const float*)d_in[8];
  const float* ln_g   = (const float*)d_in[9];
  const float* ln_b   = (const float*)d_in[10];
  const float* proj_w = (const float*)d_in[11];
  const float* proj_b = (const float*)d_in[12];

  char* W = (char*)d_ws;
  const size_t MB = 1024 * 1024;
  short* xhi   = (short*)(W);                  // 0-8
  short* WcThi = (short*)(W + 16 * MB);        // 16-18
  float* Cbuf  = (float*)(W + 20 * MB);        // 20-28 (2 partials x 4MB)
  short* LNhi  = (short*)(W + 36 * MB);        // 36-38
  short* kvThi = (short*)(W + 40 * MB);        // 40-41
  short* qThi  = (short*)(W + 42 * MB);        // 42-42.5
  short* pThi  = (short*)(W + 43 * MB);        // 43-43.5
  short* Qhi   = (short*)(W + 44 * MB);        // 44-52 (written by conv_q)
  short* Kf    = (short*)(W + 20 * MB);        // 20-22 (Cbuf dead after ln)
  short* Vf    = (short*)(W + 22 * MB);        // 22-24
  short* Ohi   = (short*)(W);                  // 0-8 (xhi dead after conv_q)

  prep_all_kernel<<<7168, 256, 0, stream>>>(
      sr_w, kv_w, q_w, proj_w, x, WcThi, kvThi, qThi, pThi, xhi);
  conv_q_kernel<<<512, 256, 0, stream>>>(
      xhi, WcThi, sr_b, Cbuf, qThi, q_b, Qhi, 0.125f * 1.44269504f);
  ln_kernel<<<2048, 256, 0, stream>>>(Cbuf, ln_g, ln_b, LNhi);
  kv_gemm_kernel<<<dim3(32, 8), 256, 0, stream>>>(LNhi, kvThi, kv_b, Kf, Vf);
  attn_kernel<<<dim3(8, 8, 8), 256, 0, stream>>>(Qhi, Kf, Vf, Ohi);
  gemm_sq<0><<<dim3(64, 4), 256, 0, stream>>>(
      Ohi, pThi, proj_b, (float*)d_out, nullptr, 1.f, 8192, 512, 512, 512);
}